// Round 1
// baseline (91.609 us; speedup 1.0000x reference)
//
#include <hip/hip_runtime.h>
#include <hip/hip_bf16.h>

#define INV_SQRT2      0.7071067811865476f
#define INV_SQRT_2PI   0.3989422804014327f

__device__ __forceinline__ float grad_gelu(float x) {
    float cdf = 0.5f * (1.0f + erff(x * INV_SQRT2));
    float pdf = INV_SQRT_2PI * __expf(-0.5f * x * x);
    return cdf + x * pdf;
}

__global__ __launch_bounds__(256) void grad_gelu_kernel(const float4* __restrict__ in,
                                                        float4* __restrict__ out,
                                                        int n4) {
    int i = blockIdx.x * blockDim.x + threadIdx.x;
    if (i < n4) {
        float4 v = in[i];
        float4 r;
        r.x = grad_gelu(v.x);
        r.y = grad_gelu(v.y);
        r.z = grad_gelu(v.z);
        r.w = grad_gelu(v.w);
        out[i] = r;
    }
}

extern "C" void kernel_launch(void* const* d_in, const int* in_sizes, int n_in,
                              void* d_out, int out_size, void* d_ws, size_t ws_size,
                              hipStream_t stream) {
    const float* x = (const float*)d_in[0];
    float* out = (float*)d_out;
    int n = in_sizes[0];           // 16*2048*2048 = 67108864, divisible by 4
    int n4 = n >> 2;
    int block = 256;
    int grid = (n4 + block - 1) / block;
    grad_gelu_kernel<<<grid, block, 0, stream>>>((const float4*)x, (float4*)out, n4);
}